// Round 1
// baseline (485.442 us; speedup 1.0000x reference)
//
#include <hip/hip_runtime.h>
#include <math.h>

#define B_ 4
#define S_ 2048
#define D_ 1024
#define H_ 8
#define N_ 128
#define HN_ 1024
#define ITERS_ 10
#define DT_ 0.1f
#define PI_ 3.14159265358979323846f
#define TWOPI_ 6.28318530717958647692f
#define INV2PI_ 0.15915494309189533577f

// Phase buffer: [B][HN][S] float32, S-contiguous. 8,388,608 floats = 33.5 MB.
__device__ float g_ph[(size_t)B_ * HN_ * S_];

// ---------------------------------------------------------------------------
// Kernel 1: ph[b][hn][s] = pi * tanh( sum_k x[b,s,k] * W_phase[k,hn] + b_phase[hn] )
// Classic 128x128x16 SGEMM, 256 threads, 8x8 microtile. Output stored transposed.
// ---------------------------------------------------------------------------
__global__ __launch_bounds__(256) void gemm_phase(const float* __restrict__ X,   // [M=8192][K=1024]
                                                  const float* __restrict__ Wp,  // [K=1024][N=1024]
                                                  const float* __restrict__ bp)  // [N]
{
    const int tid = threadIdx.x;
    const int m0 = blockIdx.x * 128;
    const int n0 = blockIdx.y * 128;

    __shared__ float As[16][132];  // [k][m], padded
    __shared__ float Bs[16][132];  // [k][n], padded

    const int tm = tid >> 4;   // 0..15
    const int tn = tid & 15;   // 0..15

    float acc[8][8] = {};

    // staging roles
    const int a_m  = tid & 127;  // A row within tile
    const int a_q  = tid >> 7;   // k half (8 k's)
    const int b_k  = tid & 15;   // B k row
    const int b_nq = tid >> 4;   // B n octet

    for (int k0 = 0; k0 < 1024; k0 += 16) {
        const float* Ap = X + (size_t)(m0 + a_m) * 1024 + k0 + 8 * a_q;
        float4 av0 = *(const float4*)Ap;
        float4 av1 = *(const float4*)(Ap + 4);
        const float* Bp = Wp + (size_t)(k0 + b_k) * 1024 + n0 + 8 * b_nq;
        float4 bv0 = *(const float4*)Bp;
        float4 bv1 = *(const float4*)(Bp + 4);

        __syncthreads();  // previous iteration's reads done before overwrite
        {
            const int kk = 8 * a_q;
            As[kk + 0][a_m] = av0.x; As[kk + 1][a_m] = av0.y;
            As[kk + 2][a_m] = av0.z; As[kk + 3][a_m] = av0.w;
            As[kk + 4][a_m] = av1.x; As[kk + 5][a_m] = av1.y;
            As[kk + 6][a_m] = av1.z; As[kk + 7][a_m] = av1.w;
            *(float4*)&Bs[b_k][8 * b_nq]     = bv0;
            *(float4*)&Bs[b_k][8 * b_nq + 4] = bv1;
        }
        __syncthreads();

        #pragma unroll
        for (int k = 0; k < 16; ++k) {
            float a0[8], b0[8];
            *(float4*)(a0)     = *(const float4*)&As[k][8 * tm];
            *(float4*)(a0 + 4) = *(const float4*)&As[k][8 * tm + 4];
            *(float4*)(b0)     = *(const float4*)&Bs[k][8 * tn];
            *(float4*)(b0 + 4) = *(const float4*)&Bs[k][8 * tn + 4];
            #pragma unroll
            for (int i = 0; i < 8; ++i)
                #pragma unroll
                for (int j = 0; j < 8; ++j)
                    acc[i][j] = fmaf(a0[i], b0[j], acc[i][j]);
        }
    }

    // epilogue: pi*tanh(acc + b), store transposed to g_ph[b][hn][s]
    const int mg0   = m0 + 8 * tm;       // global m (= b*2048 + s)
    const int ng0   = n0 + 8 * tn;       // global hn
    const int b_idx = mg0 >> 11;
    const int sg0   = mg0 & 2047;
    #pragma unroll
    for (int j = 0; j < 8; ++j) {
        const float bb = bp[ng0 + j];
        float out[8];
        #pragma unroll
        for (int i = 0; i < 8; ++i)
            out[i] = PI_ * tanhf(acc[i][j] + bb);
        float* P = g_ph + ((size_t)b_idx * HN_ + (ng0 + j)) * S_ + sg0;
        *(float4*)(P)     = *(float4*)(out);
        *(float4*)(P + 4) = *(float4*)(out + 4);
    }
}

// ---------------------------------------------------------------------------
// Kernel 2: 10 Kuramoto iterations fully in registers. One wave per (b, hn).
// Per-iteration mean over S is a wave-internal shuffle allreduce.
// ---------------------------------------------------------------------------
__global__ void kuramoto(const int* __restrict__ mask,   // [B][S]
                         const float* __restrict__ natf, // [HN]
                         const float* __restrict__ coup) // [H]
{
    const int wave = blockIdx.x * 4 + (threadIdx.x >> 6);
    const int lane = threadIdx.x & 63;
    const int b    = wave >> 10;
    const int hn   = wave & 1023;
    const int h    = hn >> 7;

    const float wf = natf[hn];
    const float K  = coup[h];

    float* base = g_ph + ((size_t)b * HN_ + hn) * S_;

    float ph[32];
    #pragma unroll
    for (int i = 0; i < 8; ++i) {
        float4 v = *(const float4*)(base + i * 256 + lane * 4);
        ph[4 * i + 0] = v.x; ph[4 * i + 1] = v.y;
        ph[4 * i + 2] = v.z; ph[4 * i + 3] = v.w;
    }

    // pack mask bits for this lane's 32 sequence positions
    const int* mb = mask + b * S_;
    unsigned int mbits = 0;
    #pragma unroll
    for (int i = 0; i < 8; ++i) {
        int4 mv = *(const int4*)(mb + i * 256 + lane * 4);
        mbits |= (mv.x != 0 ? 1u : 0u) << (4 * i + 0);
        mbits |= (mv.y != 0 ? 1u : 0u) << (4 * i + 1);
        mbits |= (mv.z != 0 ? 1u : 0u) << (4 * i + 2);
        mbits |= (mv.w != 0 ? 1u : 0u) << (4 * i + 3);
    }

    for (int it = 0; it < ITERS_; ++it) {
        float s[32], c[32];
        float ls = 0.f, lc = 0.f;
        #pragma unroll
        for (int i = 0; i < 32; ++i) {
            s[i] = __sinf(ph[i]);
            c[i] = __cosf(ph[i]);
            const float mf = (float)((mbits >> i) & 1u);
            ls = fmaf(mf, s[i], ls);
            lc = fmaf(mf, c[i], lc);
        }
        #pragma unroll
        for (int off = 32; off; off >>= 1) {
            ls += __shfl_xor(ls, off);
            lc += __shfl_xor(lc, off);
        }
        const float ms = ls * (1.f / 2048.f);
        const float mc = lc * (1.f / 2048.f);
        #pragma unroll
        for (int i = 0; i < 32; ++i) {
            const float dth = fmaf(K, fmaf(s[i], mc, -c[i] * ms), wf);
            float t = fmaf(DT_, dth, ph[i]) + PI_;
            t -= TWOPI_ * floorf(t * INV2PI_);
            ph[i] = t - PI_;
        }
    }

    #pragma unroll
    for (int i = 0; i < 8; ++i) {
        float4 v;
        v.x = ph[4 * i + 0]; v.y = ph[4 * i + 1];
        v.z = ph[4 * i + 2]; v.w = ph[4 * i + 3];
        *(float4*)(base + i * 256 + lane * 4) = v;
    }
}

// ---------------------------------------------------------------------------
// Kernel 3: y[b*S+s][d] = sum_hn ph[b][hn][s] * W_out[hn][d] + b_out[d]
// A is stored K-major (g_ph layout) -> stage directly, no transpose.
// ---------------------------------------------------------------------------
__global__ __launch_bounds__(256) void gemm_out(const float* __restrict__ Wo,  // [K=HN][N=D]
                                                const float* __restrict__ bo,  // [D]
                                                float* __restrict__ Y)         // [M=8192][D]
{
    const int tid = threadIdx.x;
    const int m0 = blockIdx.x * 128;
    const int n0 = blockIdx.y * 128;
    const int b_idx = m0 >> 11;
    const int s0 = m0 & 2047;

    __shared__ float As[16][132];  // [k][m]
    __shared__ float Bs[16][132];  // [k][n]

    const int tm = tid >> 4;
    const int tn = tid & 15;

    float acc[8][8] = {};

    const int a_k  = tid & 15;
    const int a_mq = tid >> 4;
    const int b_k  = tid & 15;
    const int b_nq = tid >> 4;

    const float* Abase = g_ph + (size_t)b_idx * HN_ * S_;

    for (int k0 = 0; k0 < 1024; k0 += 16) {
        const float* Ap = Abase + (size_t)(k0 + a_k) * S_ + s0 + 8 * a_mq;
        float4 av0 = *(const float4*)Ap;
        float4 av1 = *(const float4*)(Ap + 4);
        const float* Bp = Wo + (size_t)(k0 + b_k) * 1024 + n0 + 8 * b_nq;
        float4 bv0 = *(const float4*)Bp;
        float4 bv1 = *(const float4*)(Bp + 4);

        __syncthreads();
        *(float4*)&As[a_k][8 * a_mq]     = av0;
        *(float4*)&As[a_k][8 * a_mq + 4] = av1;
        *(float4*)&Bs[b_k][8 * b_nq]     = bv0;
        *(float4*)&Bs[b_k][8 * b_nq + 4] = bv1;
        __syncthreads();

        #pragma unroll
        for (int k = 0; k < 16; ++k) {
            float a0[8], b0[8];
            *(float4*)(a0)     = *(const float4*)&As[k][8 * tm];
            *(float4*)(a0 + 4) = *(const float4*)&As[k][8 * tm + 4];
            *(float4*)(b0)     = *(const float4*)&Bs[k][8 * tn];
            *(float4*)(b0 + 4) = *(const float4*)&Bs[k][8 * tn + 4];
            #pragma unroll
            for (int i = 0; i < 8; ++i)
                #pragma unroll
                for (int j = 0; j < 8; ++j)
                    acc[i][j] = fmaf(a0[i], b0[j], acc[i][j]);
        }
    }

    const int mg0 = m0 + 8 * tm;
    const int ng0 = n0 + 8 * tn;
    #pragma unroll
    for (int i = 0; i < 8; ++i) {
        float out[8];
        #pragma unroll
        for (int j = 0; j < 8; ++j)
            out[j] = acc[i][j] + bo[ng0 + j];
        float* Yp = Y + (size_t)(mg0 + i) * 1024 + ng0;
        *(float4*)(Yp)     = *(float4*)(out);
        *(float4*)(Yp + 4) = *(float4*)(out + 4);
    }
}

extern "C" void kernel_launch(void* const* d_in, const int* in_sizes, int n_in,
                              void* d_out, int out_size, void* d_ws, size_t ws_size,
                              hipStream_t stream) {
    const float* x    = (const float*)d_in[0];
    const int*   mask = (const int*)d_in[1];
    const float* Wp   = (const float*)d_in[2];
    const float* bp   = (const float*)d_in[3];
    const float* natf = (const float*)d_in[4];
    const float* coup = (const float*)d_in[5];
    const float* Wo   = (const float*)d_in[6];
    const float* bo   = (const float*)d_in[7];
    float* y = (float*)d_out;

    dim3 blk(256);
    dim3 gg(64, 8);  // M tiles x N tiles

    gemm_phase<<<gg, blk, 0, stream>>>(x, Wp, bp);
    kuramoto<<<dim3(1024), blk, 0, stream>>>(mask, natf, coup);
    gemm_out<<<gg, blk, 0, stream>>>(Wo, bo, y);
}

// Round 3
// 195.179 us; speedup vs baseline: 2.4872x; 2.4872x over previous
//
#include <hip/hip_runtime.h>
#include <math.h>

#define S_ 2048
#define D_ 1024
#define HN_ 1024
#define B_ 4
#define M_ 8192
#define K1_ 3072
#define K3_ 1024
#define ITERS_ 10
#define DT_ 0.1f
#define PI_ 3.14159265358979323846f
#define TWOPI_ 6.28318530717958647692f
#define INV2PI_ 0.15915494309189533577f
#define SCALE_ 4096.0f
#define INVSC2_ (1.0f / 16777216.0f)   // 2^-24

typedef __attribute__((ext_vector_type(8))) _Float16 f16x8;
typedef __attribute__((ext_vector_type(4))) float f32x4;

// static scratch
__device__ ushort g_xs [(size_t)M_ * K1_];      // x split [a|a|b] fp16, scaled 4096
__device__ ushort g_WpT[(size_t)HN_ * K1_];     // Wp^T split [a|b|a] fp16, scaled 4096
__device__ float  g_ph [(size_t)B_ * HN_ * S_]; // phases f32 [b][hn][s]
__device__ ushort g_phh[(size_t)B_ * HN_ * S_]; // final phases fp16 [b][hn][s]
__device__ ushort g_phT[(size_t)M_ * HN_];      // phases fp16 [(b,s)][hn]
__device__ ushort g_WoT[(size_t)D_ * HN_];      // Wo^T fp16 [d][hn] (unscaled)

__device__ __forceinline__ ushort f2h(float f) {
    union { _Float16 h; ushort u; } v; v.h = (_Float16)f; return v.u;
}
// x*4096 = a + b (+ ~2^-24 residual), both fp16-normal for |x| > 6e-5
__device__ __forceinline__ void split2s(float x, ushort& A, ushort& Bc) {
    const float xs = x * SCALE_;
    union { _Float16 h; ushort u; } va, vb;
    va.h = (_Float16)xs;
    const float r = xs - (float)va.h;   // exact
    vb.h = (_Float16)r;
    A = va.u; Bc = vb.u;
}
__device__ __forceinline__ void gload16(const void* g, void* l) {
    __builtin_amdgcn_global_load_lds(
        (const __attribute__((address_space(1))) void*)g,
        (__attribute__((address_space(3))) void*)l, 16, 0, 0);
}
__device__ __forceinline__ int pack2(ushort a, ushort b) {
    return (int)(unsigned)a | ((int)(unsigned)b << 16);
}

// ---------------------------------------------------------------------------
// x [8192][1024] f32 -> g_xs [8192][3072] fp16: [k: a][1024+k: a][2048+k: b]
// ---------------------------------------------------------------------------
__global__ __launch_bounds__(256) void split_x(const float* __restrict__ X) {
    const int idx = blockIdx.x * 256 + threadIdx.x;   // one float4 each
    const float4 v = ((const float4*)X)[idx];
    const int m  = idx >> 8;
    const int k4 = (idx & 255) * 4;
    ushort a[4], b[4];
    split2s(v.x, a[0], b[0]);
    split2s(v.y, a[1], b[1]);
    split2s(v.z, a[2], b[2]);
    split2s(v.w, a[3], b[3]);
    ushort* row = g_xs + (size_t)m * K1_ + k4;
    int2 oa; oa.x = pack2(a[0], a[1]); oa.y = pack2(a[2], a[3]);
    int2 ob; ob.x = pack2(b[0], b[1]); ob.y = pack2(b[2], b[3]);
    *(int2*)(row)        = oa;
    *(int2*)(row + 1024) = oa;
    *(int2*)(row + 2048) = ob;
}

// ---------------------------------------------------------------------------
// Wp [k=1024][n=1024] f32 -> g_WpT [n][3072] fp16: [k: a][1024+k: b][2048+k: a]
// ---------------------------------------------------------------------------
__global__ __launch_bounds__(256) void splitT_Wp(const float* __restrict__ Wp) {
    __shared__ float t[64][68];
    const int k0 = blockIdx.x * 64;
    const int n0 = blockIdx.y * 64;
    const int r = threadIdx.x >> 2;
    const int c = (threadIdx.x & 3) * 16;
    const float* src = Wp + (size_t)(k0 + r) * HN_ + n0 + c;
    #pragma unroll
    for (int q = 0; q < 4; ++q)
        *(float4*)&t[r][c + 4 * q] = ((const float4*)src)[q];
    __syncthreads();
    ushort ha[16], hb[16];
    #pragma unroll
    for (int j = 0; j < 16; ++j)
        split2s(t[c + j][r], ha[j], hb[j]);
    int4 a0, a1, b0, b1;
    a0.x = pack2(ha[0], ha[1]);   a0.y = pack2(ha[2], ha[3]);
    a0.z = pack2(ha[4], ha[5]);   a0.w = pack2(ha[6], ha[7]);
    a1.x = pack2(ha[8], ha[9]);   a1.y = pack2(ha[10], ha[11]);
    a1.z = pack2(ha[12], ha[13]); a1.w = pack2(ha[14], ha[15]);
    b0.x = pack2(hb[0], hb[1]);   b0.y = pack2(hb[2], hb[3]);
    b0.z = pack2(hb[4], hb[5]);   b0.w = pack2(hb[6], hb[7]);
    b1.x = pack2(hb[8], hb[9]);   b1.y = pack2(hb[10], hb[11]);
    b1.z = pack2(hb[12], hb[13]); b1.w = pack2(hb[14], hb[15]);
    ushort* dst = g_WpT + (size_t)(n0 + r) * K1_ + k0 + c;
    *(int4*)(dst)            = a0; *(int4*)(dst + 8)        = a1;
    *(int4*)(dst + 1024)     = b0; *(int4*)(dst + 1032)     = b1;
    *(int4*)(dst + 2048)     = a0; *(int4*)(dst + 2056)     = a1;
}

// ---------------------------------------------------------------------------
// Wo [hn=1024][d=1024] f32 -> g_WoT [d][hn] fp16 (transpose + cast, no scale)
// ---------------------------------------------------------------------------
__global__ __launch_bounds__(256) void castT_Wo(const float* __restrict__ Wo) {
    __shared__ float t[64][68];
    const int k0 = blockIdx.x * 64;   // hn
    const int n0 = blockIdx.y * 64;   // d
    const int r = threadIdx.x >> 2;
    const int c = (threadIdx.x & 3) * 16;
    const float* src = Wo + (size_t)(k0 + r) * D_ + n0 + c;
    #pragma unroll
    for (int q = 0; q < 4; ++q)
        *(float4*)&t[r][c + 4 * q] = ((const float4*)src)[q];
    __syncthreads();
    ushort h[16];
    #pragma unroll
    for (int j = 0; j < 16; ++j) h[j] = f2h(t[c + j][r]);
    ushort* dst = g_WoT + (size_t)(n0 + r) * HN_ + k0 + c;
    int4 o0, o1;
    o0.x = pack2(h[0], h[1]);   o0.y = pack2(h[2], h[3]);
    o0.z = pack2(h[4], h[5]);   o0.w = pack2(h[6], h[7]);
    o1.x = pack2(h[8], h[9]);   o1.y = pack2(h[10], h[11]);
    o1.z = pack2(h[12], h[13]); o1.w = pack2(h[14], h[15]);
    *(int4*)dst = o0;
    *(int4*)(dst + 8) = o1;
}

// ---------------------------------------------------------------------------
// Shared MFMA main loop: C[128m x 128n] += A[m][k] * B^T[n][k], fp16, BK=64.
// 4 waves (2x2), each 64x64 = 4x4 frags of 16x16x32.
// ---------------------------------------------------------------------------
template<int KDIM>
__device__ __forceinline__ void gemm_mainloop(const ushort* __restrict__ A,
                                              const ushort* __restrict__ Bm,
                                              ushort* As, ushort* Bs,
                                              int m0, int n0, int wid, int l,
                                              int wm, int wn,
                                              f32x4 (&acc)[4][4]) {
    const int ldrow = l >> 3;          // 0..7
    const int lcolB = (l & 7) * 16;    // bytes within 128B k-row chunk
    for (int k0 = 0; k0 < KDIM; k0 += 64) {
        #pragma unroll
        for (int j = 0; j < 4; ++j) {
            const int row = wid * 32 + j * 8 + ldrow;
            const size_t gb = (size_t)k0 * 2 + lcolB;
            gload16((const char*)(A + (size_t)(m0 + row) * KDIM) + gb,
                    (char*)As + wid * 4096 + j * 1024);
            gload16((const char*)(Bm + (size_t)(n0 + row) * KDIM) + gb,
                    (char*)Bs + wid * 4096 + j * 1024);
        }
        __syncthreads();   // compiler drains vmcnt before s_barrier
        #pragma unroll
        for (int ks = 0; ks < 2; ++ks) {
            f16x8 af[4], bf[4];
            #pragma unroll
            for (int i = 0; i < 4; ++i)
                af[i] = *(const f16x8*)(As + (wm * 64 + i * 16 + (l & 15)) * 64 + ks * 32 + (l >> 4) * 8);
            #pragma unroll
            for (int i = 0; i < 4; ++i)
                bf[i] = *(const f16x8*)(Bs + (wn * 64 + i * 16 + (l & 15)) * 64 + ks * 32 + (l >> 4) * 8);
            #pragma unroll
            for (int i = 0; i < 4; ++i)
                #pragma unroll
                for (int jj = 0; jj < 4; ++jj)
                    acc[i][jj] = __builtin_amdgcn_mfma_f32_16x16x32_f16(af[i], bf[jj], acc[i][jj], 0, 0, 0);
        }
        __syncthreads();
    }
}

// GEMM1: g_xs [8192][3072] x g_WpT[n][3072] -> pi*tanh(acc*2^-24 + bias) -> g_ph[b][n][s]
__global__ __launch_bounds__(256) void gemm1(const float* __restrict__ bias) {
    __shared__ ushort As[128 * 64];
    __shared__ ushort Bs[128 * 64];
    const int tid = threadIdx.x;
    const int wid = tid >> 6, l = tid & 63;
    const int bid = blockIdx.x;
    const int swz = (bid & 7) * 64 + (bid >> 3);   // XCD swizzle, 512%8==0
    const int m0 = (swz & 63) * 128, n0 = (swz >> 6) * 128;
    const int wm = wid >> 1, wn = wid & 1;

    f32x4 acc[4][4];
    #pragma unroll
    for (int i = 0; i < 4; ++i)
        #pragma unroll
        for (int j = 0; j < 4; ++j) acc[i][j] = (f32x4){0.f, 0.f, 0.f, 0.f};

    gemm_mainloop<K1_>(g_xs, g_WpT, As, Bs, m0, n0, wid, l, wm, wn, acc);

    const int r4 = (l >> 4) * 4;
    const int cn = l & 15;
    #pragma unroll
    for (int i = 0; i < 4; ++i) {
        const int mg = m0 + wm * 64 + i * 16 + r4;
        const int bidx = mg >> 11;
        const int sg = mg & 2047;
        #pragma unroll
        for (int jj = 0; jj < 4; ++jj) {
            const int ng = n0 + wn * 64 + jj * 16 + cn;
            const float bb = bias[ng];
            float4 o;
            o.x = PI_ * tanhf(fmaf(acc[i][jj][0], INVSC2_, bb));
            o.y = PI_ * tanhf(fmaf(acc[i][jj][1], INVSC2_, bb));
            o.z = PI_ * tanhf(fmaf(acc[i][jj][2], INVSC2_, bb));
            o.w = PI_ * tanhf(fmaf(acc[i][jj][3], INVSC2_, bb));
            *(float4*)(g_ph + ((size_t)bidx * HN_ + ng) * S_ + sg) = o;
        }
    }
}

// GEMM3: g_phT [8192][1024] x g_WoT[d][1024] + bias -> Y [8192][1024] f32
__global__ __launch_bounds__(256) void gemm3(const float* __restrict__ bias,
                                             float* __restrict__ Y) {
    __shared__ ushort As[128 * 64];
    __shared__ ushort Bs[128 * 64];
    const int tid = threadIdx.x;
    const int wid = tid >> 6, l = tid & 63;
    const int bid = blockIdx.x;
    const int swz = (bid & 7) * 64 + (bid >> 3);
    const int m0 = (swz & 63) * 128, n0 = (swz >> 6) * 128;
    const int wm = wid >> 1, wn = wid & 1;

    f32x4 acc[4][4];
    #pragma unroll
    for (int i = 0; i < 4; ++i)
        #pragma unroll
        for (int j = 0; j < 4; ++j) acc[i][j] = (f32x4){0.f, 0.f, 0.f, 0.f};

    gemm_mainloop<K3_>(g_phT, g_WoT, As, Bs, m0, n0, wid, l, wm, wn, acc);

    const int r4 = (l >> 4) * 4;
    const int cn = l & 15;
    #pragma unroll
    for (int i = 0; i < 4; ++i) {
        const int mg = m0 + wm * 64 + i * 16 + r4;
        #pragma unroll
        for (int jj = 0; jj < 4; ++jj) {
            const int ng = n0 + wn * 64 + jj * 16 + cn;
            const float bb = bias[ng];
            #pragma unroll
            for (int r = 0; r < 4; ++r)
                Y[(size_t)(mg + r) * D_ + ng] = acc[i][jj][r] + bb;
        }
    }
}

// ---------------------------------------------------------------------------
// Kuramoto: one wave per (b, hn), 32 phases/lane, 10 iters in registers.
// Reads g_ph f32, writes g_phh fp16.
// ---------------------------------------------------------------------------
__global__ __launch_bounds__(256) void kuramoto(const int* __restrict__ mask,
                                                const float* __restrict__ natf,
                                                const float* __restrict__ coup) {
    const int wave = blockIdx.x * 4 + (threadIdx.x >> 6);
    const int lane = threadIdx.x & 63;
    const int b = wave >> 10;
    const int hn = wave & 1023;
    const int h = hn >> 7;

    const float wf = natf[hn];
    const float K = coup[h];

    const float* base = g_ph + ((size_t)b * HN_ + hn) * S_;

    float ph[32];
    #pragma unroll
    for (int i = 0; i < 8; ++i) {
        float4 v = *(const float4*)(base + i * 256 + lane * 4);
        ph[4 * i + 0] = v.x; ph[4 * i + 1] = v.y;
        ph[4 * i + 2] = v.z; ph[4 * i + 3] = v.w;
    }

    const int* mb = mask + b * S_;
    unsigned mbits = 0;
    #pragma unroll
    for (int i = 0; i < 8; ++i) {
        int4 mv = *(const int4*)(mb + i * 256 + lane * 4);
        mbits |= (mv.x != 0 ? 1u : 0u) << (4 * i + 0);
        mbits |= (mv.y != 0 ? 1u : 0u) << (4 * i + 1);
        mbits |= (mv.z != 0 ? 1u : 0u) << (4 * i + 2);
        mbits |= (mv.w != 0 ? 1u : 0u) << (4 * i + 3);
    }

    for (int it = 0; it < ITERS_; ++it) {
        float s[32], c[32];
        float ls = 0.f, lc = 0.f;
        #pragma unroll
        for (int i = 0; i < 32; ++i) {
            s[i] = __sinf(ph[i]);
            c[i] = __cosf(ph[i]);
            const float mf = (float)((mbits >> i) & 1u);
            ls = fmaf(mf, s[i], ls);
            lc = fmaf(mf, c[i], lc);
        }
        #pragma unroll
        for (int off = 32; off; off >>= 1) {
            ls += __shfl_xor(ls, off);
            lc += __shfl_xor(lc, off);
        }
        const float ms = ls * (1.f / 2048.f);
        const float mc = lc * (1.f / 2048.f);
        #pragma unroll
        for (int i = 0; i < 32; ++i) {
            const float dth = fmaf(K, fmaf(s[i], mc, -c[i] * ms), wf);
            float t = fmaf(DT_, dth, ph[i]) + PI_;
            t -= TWOPI_ * floorf(t * INV2PI_);
            ph[i] = t - PI_;
        }
    }

    ushort* ob = g_phh + ((size_t)b * HN_ + hn) * S_;
    #pragma unroll
    for (int i = 0; i < 8; ++i) {
        ushort4 o;
        o.x = f2h(ph[4 * i + 0]); o.y = f2h(ph[4 * i + 1]);
        o.z = f2h(ph[4 * i + 2]); o.w = f2h(ph[4 * i + 3]);
        *(ushort4*)(ob + i * 256 + lane * 4) = o;
    }
}

// ---------------------------------------------------------------------------
// g_phh [b][hn][s] fp16 -> g_phT [(b,s)][hn] fp16  (64x64 tiles)
// ---------------------------------------------------------------------------
__global__ __launch_bounds__(256) void transpose_ph() {
    __shared__ ushort t[64][72];
    const int b = blockIdx.z;
    const int h0 = blockIdx.y * 64;
    const int s0 = blockIdx.x * 64;
    const int r = threadIdx.x >> 2;
    const int c = (threadIdx.x & 3) * 16;
    const ushort* src = g_phh + ((size_t)b * HN_ + h0 + r) * S_ + s0 + c;
    *(int4*)&t[r][c] = *(const int4*)src;
    *(int4*)&t[r][c + 8] = *(const int4*)(src + 8);
    __syncthreads();
    ushort o[16];
    #pragma unroll
    for (int j = 0; j < 16; ++j) o[j] = t[c + j][r];
    ushort* dst = g_phT + ((size_t)(b * S_ + s0 + r)) * HN_ + h0 + c;
    int4 o0, o1;
    o0.x = pack2(o[0], o[1]);   o0.y = pack2(o[2], o[3]);
    o0.z = pack2(o[4], o[5]);   o0.w = pack2(o[6], o[7]);
    o1.x = pack2(o[8], o[9]);   o1.y = pack2(o[10], o[11]);
    o1.z = pack2(o[12], o[13]); o1.w = pack2(o[14], o[15]);
    *(int4*)dst = o0;
    *(int4*)(dst + 8) = o1;
}

extern "C" void kernel_launch(void* const* d_in, const int* in_sizes, int n_in,
                              void* d_out, int out_size, void* d_ws, size_t ws_size,
                              hipStream_t stream) {
    const float* x    = (const float*)d_in[0];
    const int*   mask = (const int*)d_in[1];
    const float* Wp   = (const float*)d_in[2];
    const float* bp   = (const float*)d_in[3];
    const float* natf = (const float*)d_in[4];
    const float* coup = (const float*)d_in[5];
    const float* Wo   = (const float*)d_in[6];
    const float* bo   = (const float*)d_in[7];
    float* y = (float*)d_out;

    split_x  <<<dim3(8192),        256, 0, stream>>>(x);
    splitT_Wp<<<dim3(16, 16),      256, 0, stream>>>(Wp);
    castT_Wo <<<dim3(16, 16),      256, 0, stream>>>(Wo);
    gemm1    <<<dim3(512),         256, 0, stream>>>(bp);
    kuramoto <<<dim3(1024),        256, 0, stream>>>(mask, natf, coup);
    transpose_ph<<<dim3(32, 16, 4), 256, 0, stream>>>();
    gemm3    <<<dim3(512),         256, 0, stream>>>(bo, y);
}

// Round 4
// 173.968 us; speedup vs baseline: 2.7904x; 1.1219x over previous
//
#include <hip/hip_runtime.h>
#include <math.h>

#define S_ 2048
#define D_ 1024
#define HN_ 1024
#define B_ 4
#define M_ 8192
#define K1_ 3072
#define K3_ 1024
#define ITERS_ 10
#define DT_ 0.1f
#define PI_ 3.14159265358979323846f
#define TWOPI_ 6.28318530717958647692f
#define INV2PI_ 0.15915494309189533577f
#define SCALE_ 4096.0f
#define INVSC2_ (1.0f / 16777216.0f)   // 2^-24

typedef __attribute__((ext_vector_type(8))) _Float16 f16x8;
typedef __attribute__((ext_vector_type(4))) float f32x4;

// static scratch
__device__ ushort g_xs [(size_t)M_ * K1_];      // x split [a|a|b] fp16, scaled 4096
__device__ ushort g_WpT[(size_t)HN_ * K1_];     // Wp^T split [a|b|a] fp16, scaled 4096
__device__ float  g_ph [(size_t)B_ * HN_ * S_]; // phases f32 [b][hn][s]
__device__ ushort g_phh[(size_t)B_ * HN_ * S_]; // final phases fp16 [b][hn][s]
__device__ ushort g_phT[(size_t)M_ * HN_];      // phases fp16 [(b,s)][hn]
__device__ ushort g_WoT[(size_t)D_ * HN_];      // Wo^T fp16 [d][hn] (unscaled)

__device__ __forceinline__ ushort f2h(float f) {
    union { _Float16 h; ushort u; } v; v.h = (_Float16)f; return v.u;
}
__device__ __forceinline__ void split2s(float x, ushort& A, ushort& Bc) {
    const float xs = x * SCALE_;
    union { _Float16 h; ushort u; } va, vb;
    va.h = (_Float16)xs;
    const float r = xs - (float)va.h;   // exact
    vb.h = (_Float16)r;
    A = va.u; Bc = vb.u;
}
__device__ __forceinline__ void gload16(const void* g, void* l) {
    __builtin_amdgcn_global_load_lds(
        (const __attribute__((address_space(1))) void*)g,
        (__attribute__((address_space(3))) void*)l, 16, 0, 0);
}
__device__ __forceinline__ int pack2(ushort a, ushort b) {
    return (int)(unsigned)a | ((int)(unsigned)b << 16);
}

// ---------------------------------------------------------------------------
// prep kernels (unchanged from round 3, verified)
// ---------------------------------------------------------------------------
__global__ __launch_bounds__(256) void split_x(const float* __restrict__ X) {
    const int idx = blockIdx.x * 256 + threadIdx.x;
    const float4 v = ((const float4*)X)[idx];
    const int m  = idx >> 8;
    const int k4 = (idx & 255) * 4;
    ushort a[4], b[4];
    split2s(v.x, a[0], b[0]);
    split2s(v.y, a[1], b[1]);
    split2s(v.z, a[2], b[2]);
    split2s(v.w, a[3], b[3]);
    ushort* row = g_xs + (size_t)m * K1_ + k4;
    int2 oa; oa.x = pack2(a[0], a[1]); oa.y = pack2(a[2], a[3]);
    int2 ob; ob.x = pack2(b[0], b[1]); ob.y = pack2(b[2], b[3]);
    *(int2*)(row)        = oa;
    *(int2*)(row + 1024) = oa;
    *(int2*)(row + 2048) = ob;
}

__global__ __launch_bounds__(256) void splitT_Wp(const float* __restrict__ Wp) {
    __shared__ float t[64][68];
    const int k0 = blockIdx.x * 64;
    const int n0 = blockIdx.y * 64;
    const int r = threadIdx.x >> 2;
    const int c = (threadIdx.x & 3) * 16;
    const float* src = Wp + (size_t)(k0 + r) * HN_ + n0 + c;
    #pragma unroll
    for (int q = 0; q < 4; ++q)
        *(float4*)&t[r][c + 4 * q] = ((const float4*)src)[q];
    __syncthreads();
    ushort ha[16], hb[16];
    #pragma unroll
    for (int j = 0; j < 16; ++j)
        split2s(t[c + j][r], ha[j], hb[j]);
    int4 a0, a1, b0, b1;
    a0.x = pack2(ha[0], ha[1]);   a0.y = pack2(ha[2], ha[3]);
    a0.z = pack2(ha[4], ha[5]);   a0.w = pack2(ha[6], ha[7]);
    a1.x = pack2(ha[8], ha[9]);   a1.y = pack2(ha[10], ha[11]);
    a1.z = pack2(ha[12], ha[13]); a1.w = pack2(ha[14], ha[15]);
    b0.x = pack2(hb[0], hb[1]);   b0.y = pack2(hb[2], hb[3]);
    b0.z = pack2(hb[4], hb[5]);   b0.w = pack2(hb[6], hb[7]);
    b1.x = pack2(hb[8], hb[9]);   b1.y = pack2(hb[10], hb[11]);
    b1.z = pack2(hb[12], hb[13]); b1.w = pack2(hb[14], hb[15]);
    ushort* dst = g_WpT + (size_t)(n0 + r) * K1_ + k0 + c;
    *(int4*)(dst)            = a0; *(int4*)(dst + 8)        = a1;
    *(int4*)(dst + 1024)     = b0; *(int4*)(dst + 1032)     = b1;
    *(int4*)(dst + 2048)     = a0; *(int4*)(dst + 2056)     = a1;
}

__global__ __launch_bounds__(256) void castT_Wo(const float* __restrict__ Wo) {
    __shared__ float t[64][68];
    const int k0 = blockIdx.x * 64;   // hn
    const int n0 = blockIdx.y * 64;   // d
    const int r = threadIdx.x >> 2;
    const int c = (threadIdx.x & 3) * 16;
    const float* src = Wo + (size_t)(k0 + r) * D_ + n0 + c;
    #pragma unroll
    for (int q = 0; q < 4; ++q)
        *(float4*)&t[r][c + 4 * q] = ((const float4*)src)[q];
    __syncthreads();
    ushort h[16];
    #pragma unroll
    for (int j = 0; j < 16; ++j) h[j] = f2h(t[c + j][r]);
    ushort* dst = g_WoT + (size_t)(n0 + r) * HN_ + k0 + c;
    int4 o0, o1;
    o0.x = pack2(h[0], h[1]);   o0.y = pack2(h[2], h[3]);
    o0.z = pack2(h[4], h[5]);   o0.w = pack2(h[6], h[7]);
    o1.x = pack2(h[8], h[9]);   o1.y = pack2(h[10], h[11]);
    o1.z = pack2(h[12], h[13]); o1.w = pack2(h[14], h[15]);
    *(int4*)dst = o0;
    *(int4*)(dst + 8) = o1;
}

// ---------------------------------------------------------------------------
// MFMA main loop, BM=256 x BN=128, BK=64, 8 waves (4M x 2N), 512 threads.
// 3-deep pipelined: 3 LDS buffers (48KB each: A 32KB + B 16KB), counted
// vmcnt(6) (= one tile's 6 loads/wave x 1 younger tile in flight), single
// s_barrier per K-step placed BEFORE the stage-issue (protects buffer reuse).
// T2 XOR-swizzle (byte ^ ((row&7)<<4)) applied on BOTH the global source of
// global_load_lds (inverse permutation, LDS dest stays linear) and the
// ds_read address.
// ---------------------------------------------------------------------------
template<int KDIM>
__device__ __forceinline__ void gemm_mainloop(const ushort* __restrict__ A,
                                              const ushort* __restrict__ Bm,
                                              ushort* lds,
                                              int m0, int n0, int wid, int l,
                                              int wm, int wn,
                                              f32x4 (&acc)[4][4]) {
    constexpr int NT = KDIM / 64;
    const int r8   = l >> 3;                         // 0..7 (row within 8-row chunk)
    const int swzo = ((l & 7) * 16) ^ (r8 << 4);     // swizzled byte off in 128B window

    #define STAGE(T, BUF) do {                                                   \
        const size_t gb_ = (size_t)(T) * 128 + swzo;                             \
        char* ab_ = (char*)lds + (BUF) * 49152;                                  \
        _Pragma("unroll")                                                        \
        for (int j_ = 0; j_ < 4; ++j_) {                                         \
            const int c_ = wid * 4 + j_;                                         \
            gload16((const char*)(A + (size_t)(m0 + c_ * 8 + r8) * KDIM) + gb_,  \
                    ab_ + c_ * 1024);                                            \
        }                                                                        \
        _Pragma("unroll")                                                        \
        for (int j_ = 0; j_ < 2; ++j_) {                                         \
            const int c_ = wid * 2 + j_;                                         \
            gload16((const char*)(Bm + (size_t)(n0 + c_ * 8 + r8) * KDIM) + gb_, \
                    ab_ + 32768 + c_ * 1024);                                    \
        }                                                                        \
    } while (0)

    STAGE(0, 0);
    STAGE(1, 1);

    for (int t = 0; t < NT; ++t) {
        if (t < NT - 1) asm volatile("s_waitcnt vmcnt(6)" ::: "memory");
        else            asm volatile("s_waitcnt vmcnt(0)" ::: "memory");
        __builtin_amdgcn_sched_barrier(0);
        __builtin_amdgcn_s_barrier();
        __builtin_amdgcn_sched_barrier(0);
        if (t + 2 < NT) STAGE(t + 2, (t + 2) % 3);

        const char* ab = (const char*)lds + (t % 3) * 49152;
        const char* bb = ab + 32768;
        #pragma unroll
        for (int ks = 0; ks < 2; ++ks) {
            const int kb = ks * 64 + (l >> 4) * 16;
            f16x8 af[4], bf[4];
            #pragma unroll
            for (int i = 0; i < 4; ++i) {
                const int r = wm * 64 + i * 16 + (l & 15);
                af[i] = *(const f16x8*)(ab + r * 128 + (kb ^ ((r & 7) << 4)));
            }
            #pragma unroll
            for (int i = 0; i < 4; ++i) {
                const int r = wn * 64 + i * 16 + (l & 15);
                bf[i] = *(const f16x8*)(bb + r * 128 + (kb ^ ((r & 7) << 4)));
            }
            __builtin_amdgcn_s_setprio(1);
            #pragma unroll
            for (int i = 0; i < 4; ++i)
                #pragma unroll
                for (int jj = 0; jj < 4; ++jj)
                    acc[i][jj] = __builtin_amdgcn_mfma_f32_16x16x32_f16(af[i], bf[jj], acc[i][jj], 0, 0, 0);
            __builtin_amdgcn_s_setprio(0);
        }
    }
    #undef STAGE
}

// GEMM1: g_xs [8192][3072] x g_WpT[n][3072] -> pi*tanh(acc*2^-24 + bias) -> g_ph[b][n][s]
__global__ __launch_bounds__(512) void gemm1(const float* __restrict__ bias) {
    __shared__ ushort lds[3 * 24576];   // 144 KB
    const int tid = threadIdx.x;
    const int wid = tid >> 6, l = tid & 63;
    const int bid = blockIdx.x;
    const int swz = (bid & 7) * 32 + (bid >> 3);   // 256 blocks, 8 XCD chunks
    const int m0 = (swz & 31) * 256, n0 = (swz >> 5) * 128;
    const int wm = wid >> 1, wn = wid & 1;

    f32x4 acc[4][4];
    #pragma unroll
    for (int i = 0; i < 4; ++i)
        #pragma unroll
        for (int j = 0; j < 4; ++j) acc[i][j] = (f32x4){0.f, 0.f, 0.f, 0.f};

    gemm_mainloop<K1_>(g_xs, g_WpT, lds, m0, n0, wid, l, wm, wn, acc);

    const int r4 = (l >> 4) * 4;
    const int cn = l & 15;
    #pragma unroll
    for (int i = 0; i < 4; ++i) {
        const int mg = m0 + wm * 64 + i * 16 + r4;
        const int bidx = mg >> 11;
        const int sg = mg & 2047;
        #pragma unroll
        for (int jj = 0; jj < 4; ++jj) {
            const int ng = n0 + wn * 64 + jj * 16 + cn;
            const float bb = bias[ng];
            float4 o;
            o.x = PI_ * tanhf(fmaf(acc[i][jj][0], INVSC2_, bb));
            o.y = PI_ * tanhf(fmaf(acc[i][jj][1], INVSC2_, bb));
            o.z = PI_ * tanhf(fmaf(acc[i][jj][2], INVSC2_, bb));
            o.w = PI_ * tanhf(fmaf(acc[i][jj][3], INVSC2_, bb));
            *(float4*)(g_ph + ((size_t)bidx * HN_ + ng) * S_ + sg) = o;
        }
    }
}

// GEMM3: g_phT [8192][1024] x g_WoT[d][1024] + bias -> Y [8192][1024] f32
__global__ __launch_bounds__(512) void gemm3(const float* __restrict__ bias,
                                             float* __restrict__ Y) {
    __shared__ ushort lds[3 * 24576];   // 144 KB
    const int tid = threadIdx.x;
    const int wid = tid >> 6, l = tid & 63;
    const int bid = blockIdx.x;
    const int swz = (bid & 7) * 32 + (bid >> 3);
    const int m0 = (swz & 31) * 256, n0 = (swz >> 5) * 128;
    const int wm = wid >> 1, wn = wid & 1;

    f32x4 acc[4][4];
    #pragma unroll
    for (int i = 0; i < 4; ++i)
        #pragma unroll
        for (int j = 0; j < 4; ++j) acc[i][j] = (f32x4){0.f, 0.f, 0.f, 0.f};

    gemm_mainloop<K3_>(g_phT, g_WoT, lds, m0, n0, wid, l, wm, wn, acc);

    const int r4 = (l >> 4) * 4;
    const int cn = l & 15;
    #pragma unroll
    for (int i = 0; i < 4; ++i) {
        const int mg = m0 + wm * 64 + i * 16 + r4;
        #pragma unroll
        for (int jj = 0; jj < 4; ++jj) {
            const int ng = n0 + wn * 64 + jj * 16 + cn;
            const float bb = bias[ng];
            #pragma unroll
            for (int r = 0; r < 4; ++r)
                Y[(size_t)(mg + r) * D_ + ng] = acc[i][jj][r] + bb;
        }
    }
}

// ---------------------------------------------------------------------------
// Kuramoto (unchanged, verified): one wave per (b, hn), 10 iters in registers.
// ---------------------------------------------------------------------------
__global__ __launch_bounds__(256) void kuramoto(const int* __restrict__ mask,
                                                const float* __restrict__ natf,
                                                const float* __restrict__ coup) {
    const int wave = blockIdx.x * 4 + (threadIdx.x >> 6);
    const int lane = threadIdx.x & 63;
    const int b = wave >> 10;
    const int hn = wave & 1023;
    const int h = hn >> 7;

    const float wf = natf[hn];
    const float K = coup[h];

    const float* base = g_ph + ((size_t)b * HN_ + hn) * S_;

    float ph[32];
    #pragma unroll
    for (int i = 0; i < 8; ++i) {
        float4 v = *(const float4*)(base + i * 256 + lane * 4);
        ph[4 * i + 0] = v.x; ph[4 * i + 1] = v.y;
        ph[4 * i + 2] = v.z; ph[4 * i + 3] = v.w;
    }

    const int* mb = mask + b * S_;
    unsigned mbits = 0;
    #pragma unroll
    for (int i = 0; i < 8; ++i) {
        int4 mv = *(const int4*)(mb + i * 256 + lane * 4);
        mbits |= (mv.x != 0 ? 1u : 0u) << (4 * i + 0);
        mbits |= (mv.y != 0 ? 1u : 0u) << (4 * i + 1);
        mbits |= (mv.z != 0 ? 1u : 0u) << (4 * i + 2);
        mbits |= (mv.w != 0 ? 1u : 0u) << (4 * i + 3);
    }

    for (int it = 0; it < ITERS_; ++it) {
        float s[32], c[32];
        float ls = 0.f, lc = 0.f;
        #pragma unroll
        for (int i = 0; i < 32; ++i) {
            s[i] = __sinf(ph[i]);
            c[i] = __cosf(ph[i]);
            const float mf = (float)((mbits >> i) & 1u);
            ls = fmaf(mf, s[i], ls);
            lc = fmaf(mf, c[i], lc);
        }
        #pragma unroll
        for (int off = 32; off; off >>= 1) {
            ls += __shfl_xor(ls, off);
            lc += __shfl_xor(lc, off);
        }
        const float ms = ls * (1.f / 2048.f);
        const float mc = lc * (1.f / 2048.f);
        #pragma unroll
        for (int i = 0; i < 32; ++i) {
            const float dth = fmaf(K, fmaf(s[i], mc, -c[i] * ms), wf);
            float t = fmaf(DT_, dth, ph[i]) + PI_;
            t -= TWOPI_ * floorf(t * INV2PI_);
            ph[i] = t - PI_;
        }
    }

    ushort* ob = g_phh + ((size_t)b * HN_ + hn) * S_;
    #pragma unroll
    for (int i = 0; i < 8; ++i) {
        ushort4 o;
        o.x = f2h(ph[4 * i + 0]); o.y = f2h(ph[4 * i + 1]);
        o.z = f2h(ph[4 * i + 2]); o.w = f2h(ph[4 * i + 3]);
        *(ushort4*)(ob + i * 256 + lane * 4) = o;
    }
}

// ---------------------------------------------------------------------------
// g_phh [b][hn][s] fp16 -> g_phT [(b,s)][hn] fp16  (64x64 tiles, unchanged)
// ---------------------------------------------------------------------------
__global__ __launch_bounds__(256) void transpose_ph() {
    __shared__ ushort t[64][72];
    const int b = blockIdx.z;
    const int h0 = blockIdx.y * 64;
    const int s0 = blockIdx.x * 64;
    const int r = threadIdx.x >> 2;
    const int c = (threadIdx.x & 3) * 16;
    const ushort* src = g_phh + ((size_t)b * HN_ + h0 + r) * S_ + s0 + c;
    *(int4*)&t[r][c] = *(const int4*)src;
    *(int4*)&t[r][c + 8] = *(const int4*)(src + 8);
    __syncthreads();
    ushort o[16];
    #pragma unroll
    for (int j = 0; j < 16; ++j) o[j] = t[c + j][r];
    ushort* dst = g_phT + ((size_t)(b * S_ + s0 + r)) * HN_ + h0 + c;
    int4 o0, o1;
    o0.x = pack2(o[0], o[1]);   o0.y = pack2(o[2], o[3]);
    o0.z = pack2(o[4], o[5]);   o0.w = pack2(o[6], o[7]);
    o1.x = pack2(o[8], o[9]);   o1.y = pack2(o[10], o[11]);
    o1.z = pack2(o[12], o[13]); o1.w = pack2(o[14], o[15]);
    *(int4*)dst = o0;
    *(int4*)(dst + 8) = o1;
}

extern "C" void kernel_launch(void* const* d_in, const int* in_sizes, int n_in,
                              void* d_out, int out_size, void* d_ws, size_t ws_size,
                              hipStream_t stream) {
    const float* x    = (const float*)d_in[0];
    const int*   mask = (const int*)d_in[1];
    const float* Wp   = (const float*)d_in[2];
    const float* bp   = (const float*)d_in[3];
    const float* natf = (const float*)d_in[4];
    const float* coup = (const float*)d_in[5];
    const float* Wo   = (const float*)d_in[6];
    const float* bo   = (const float*)d_in[7];
    float* y = (float*)d_out;

    split_x  <<<dim3(8192),         256, 0, stream>>>(x);
    splitT_Wp<<<dim3(16, 16),       256, 0, stream>>>(Wp);
    castT_Wo <<<dim3(16, 16),       256, 0, stream>>>(Wo);
    gemm1    <<<dim3(256),          512, 0, stream>>>(bp);
    kuramoto <<<dim3(1024),         256, 0, stream>>>(mask, natf, coup);
    transpose_ph<<<dim3(32, 16, 4), 256, 0, stream>>>();
    gemm3    <<<dim3(256),          512, 0, stream>>>(bo, y);
}

// Round 5
// 158.729 us; speedup vs baseline: 3.0583x; 1.0960x over previous
//
#include <hip/hip_runtime.h>
#include <math.h>

#define S_ 2048
#define D_ 1024
#define HN_ 1024
#define B_ 4
#define M_ 8192
#define K1_ 3072
#define K3_ 1024
#define ITERS_ 10
#define DT_ 0.1f
#define PI_ 3.14159265358979323846f
#define TWOPI_ 6.28318530717958647692f
#define INV2PI_ 0.15915494309189533577f
#define SCALE_ 4096.0f
#define INVSC2_ (1.0f / 16777216.0f)   // 2^-24

typedef __attribute__((ext_vector_type(8))) _Float16 f16x8;
typedef __attribute__((ext_vector_type(4))) float f32x4;

// static scratch
__device__ ushort g_xs [(size_t)M_ * K1_];      // x split [a|a|b] fp16, scaled 4096
__device__ ushort g_WpT[(size_t)HN_ * K1_];     // Wp^T split [a|b|a] fp16, scaled 4096
__device__ float  g_ph [(size_t)B_ * HN_ * S_]; // phases f32 [b][hn][s]
__device__ ushort g_phh[(size_t)B_ * HN_ * S_]; // final phases fp16 [b][hn][s]
__device__ ushort g_phT[(size_t)M_ * HN_];      // phases fp16 [(b,s)][hn]
__device__ ushort g_WoT[(size_t)D_ * HN_];      // Wo^T fp16 [d][hn] (unscaled)

__device__ __forceinline__ ushort f2h(float f) {
    union { _Float16 h; ushort u; } v; v.h = (_Float16)f; return v.u;
}
__device__ __forceinline__ void split2s(float x, ushort& A, ushort& Bc) {
    const float xs = x * SCALE_;
    union { _Float16 h; ushort u; } va, vb;
    va.h = (_Float16)xs;
    const float r = xs - (float)va.h;   // exact
    vb.h = (_Float16)r;
    A = va.u; Bc = vb.u;
}
__device__ __forceinline__ void gload16(const void* g, void* l) {
    __builtin_amdgcn_global_load_lds(
        (const __attribute__((address_space(1))) void*)g,
        (__attribute__((address_space(3))) void*)l, 16, 0, 0);
}
__device__ __forceinline__ int pack2(ushort a, ushort b) {
    return (int)(unsigned)a | ((int)(unsigned)b << 16);
}

// ---------------------------------------------------------------------------
// prep kernels (unchanged, verified)
// ---------------------------------------------------------------------------
__global__ __launch_bounds__(256) void split_x(const float* __restrict__ X) {
    const int idx = blockIdx.x * 256 + threadIdx.x;
    const float4 v = ((const float4*)X)[idx];
    const int m  = idx >> 8;
    const int k4 = (idx & 255) * 4;
    ushort a[4], b[4];
    split2s(v.x, a[0], b[0]);
    split2s(v.y, a[1], b[1]);
    split2s(v.z, a[2], b[2]);
    split2s(v.w, a[3], b[3]);
    ushort* row = g_xs + (size_t)m * K1_ + k4;
    int2 oa; oa.x = pack2(a[0], a[1]); oa.y = pack2(a[2], a[3]);
    int2 ob; ob.x = pack2(b[0], b[1]); ob.y = pack2(b[2], b[3]);
    *(int2*)(row)        = oa;
    *(int2*)(row + 1024) = oa;
    *(int2*)(row + 2048) = ob;
}

__global__ __launch_bounds__(256) void splitT_Wp(const float* __restrict__ Wp) {
    __shared__ float t[64][68];
    const int k0 = blockIdx.x * 64;
    const int n0 = blockIdx.y * 64;
    const int r = threadIdx.x >> 2;
    const int c = (threadIdx.x & 3) * 16;
    const float* src = Wp + (size_t)(k0 + r) * HN_ + n0 + c;
    #pragma unroll
    for (int q = 0; q < 4; ++q)
        *(float4*)&t[r][c + 4 * q] = ((const float4*)src)[q];
    __syncthreads();
    ushort ha[16], hb[16];
    #pragma unroll
    for (int j = 0; j < 16; ++j)
        split2s(t[c + j][r], ha[j], hb[j]);
    int4 a0, a1, b0, b1;
    a0.x = pack2(ha[0], ha[1]);   a0.y = pack2(ha[2], ha[3]);
    a0.z = pack2(ha[4], ha[5]);   a0.w = pack2(ha[6], ha[7]);
    a1.x = pack2(ha[8], ha[9]);   a1.y = pack2(ha[10], ha[11]);
    a1.z = pack2(ha[12], ha[13]); a1.w = pack2(ha[14], ha[15]);
    b0.x = pack2(hb[0], hb[1]);   b0.y = pack2(hb[2], hb[3]);
    b0.z = pack2(hb[4], hb[5]);   b0.w = pack2(hb[6], hb[7]);
    b1.x = pack2(hb[8], hb[9]);   b1.y = pack2(hb[10], hb[11]);
    b1.z = pack2(hb[12], hb[13]); b1.w = pack2(hb[14], hb[15]);
    ushort* dst = g_WpT + (size_t)(n0 + r) * K1_ + k0 + c;
    *(int4*)(dst)            = a0; *(int4*)(dst + 8)        = a1;
    *(int4*)(dst + 1024)     = b0; *(int4*)(dst + 1032)     = b1;
    *(int4*)(dst + 2048)     = a0; *(int4*)(dst + 2056)     = a1;
}

__global__ __launch_bounds__(256) void castT_Wo(const float* __restrict__ Wo) {
    __shared__ float t[64][68];
    const int k0 = blockIdx.x * 64;   // hn
    const int n0 = blockIdx.y * 64;   // d
    const int r = threadIdx.x >> 2;
    const int c = (threadIdx.x & 3) * 16;
    const float* src = Wo + (size_t)(k0 + r) * D_ + n0 + c;
    #pragma unroll
    for (int q = 0; q < 4; ++q)
        *(float4*)&t[r][c + 4 * q] = ((const float4*)src)[q];
    __syncthreads();
    ushort h[16];
    #pragma unroll
    for (int j = 0; j < 16; ++j) h[j] = f2h(t[c + j][r]);
    ushort* dst = g_WoT + (size_t)(n0 + r) * HN_ + k0 + c;
    int4 o0, o1;
    o0.x = pack2(h[0], h[1]);   o0.y = pack2(h[2], h[3]);
    o0.z = pack2(h[4], h[5]);   o0.w = pack2(h[6], h[7]);
    o1.x = pack2(h[8], h[9]);   o1.y = pack2(h[10], h[11]);
    o1.z = pack2(h[12], h[13]); o1.w = pack2(h[14], h[15]);
    *(int4*)dst = o0;
    *(int4*)(dst + 8) = o1;
}

// ---------------------------------------------------------------------------
// MFMA main loop, BM=256 x BN=128, BK=64, 8 waves (4M x 2N), 512 threads.
// 3-deep pipelined (3 x 48KB LDS buffers), counted vmcnt(6) once per K-tile.
// Split into 2 phases per K-tile (ks=0,1): each phase = {8 ds_read_b128 ||
// half-stage issue -> s_barrier -> lgkmcnt(0) -> setprio(1) 16 MFMA}.
// Race audit: STAGE(t+2) writes buf[(t-1)%3]; every wave's ds_reads of that
// buffer were drained (its own lgkmcnt(0)) before its phase-1 MFMA, which
// precedes the top barrier of iter t, which precedes any STAGE(t+2) issue.
// T2 XOR swizzle on both global source (inverse perm) and ds_read address.
// ---------------------------------------------------------------------------
template<int KDIM>
__device__ __forceinline__ void gemm_mainloop(const ushort* __restrict__ A,
                                              const ushort* __restrict__ Bm,
                                              ushort* lds,
                                              int m0, int n0, int wid, int l,
                                              int wm, int wn,
                                              f32x4 (&acc)[4][4]) {
    constexpr int NT = KDIM / 64;
    const int r8   = l >> 3;                         // 0..7
    const int swzo = ((l & 7) * 16) ^ (r8 << 4);     // swizzled byte off in 128B window

    #define STAGE_A(T, BUF) do {                                                 \
        const size_t gb_ = (size_t)(T) * 128 + swzo;                             \
        char* ab_ = (char*)lds + (BUF) * 49152;                                  \
        _Pragma("unroll")                                                        \
        for (int j_ = 0; j_ < 4; ++j_) {                                         \
            const int c_ = wid * 4 + j_;                                         \
            gload16((const char*)(A + (size_t)(m0 + c_ * 8 + r8) * KDIM) + gb_,  \
                    ab_ + c_ * 1024);                                            \
        }                                                                        \
    } while (0)
    #define STAGE_B(T, BUF) do {                                                 \
        const size_t gb_ = (size_t)(T) * 128 + swzo;                             \
        char* bb_ = (char*)lds + (BUF) * 49152 + 32768;                          \
        _Pragma("unroll")                                                        \
        for (int j_ = 0; j_ < 2; ++j_) {                                         \
            const int c_ = wid * 2 + j_;                                         \
            gload16((const char*)(Bm + (size_t)(n0 + c_ * 8 + r8) * KDIM) + gb_, \
                    bb_ + c_ * 1024);                                            \
        }                                                                        \
    } while (0)

    STAGE_A(0, 0); STAGE_B(0, 0);
    STAGE_A(1, 1); STAGE_B(1, 1);

    for (int t = 0; t < NT; ++t) {
        if (t < NT - 1) asm volatile("s_waitcnt vmcnt(6)" ::: "memory");
        else            asm volatile("s_waitcnt vmcnt(0)" ::: "memory");
        __builtin_amdgcn_sched_barrier(0);
        __builtin_amdgcn_s_barrier();
        __builtin_amdgcn_sched_barrier(0);

        const char* ab = (const char*)lds + (t % 3) * 49152;
        const char* bb = ab + 32768;

        f16x8 af[4], bf[4];

        // ===== phase 0: ks = 0 =====
        {
            const int kb = (l >> 4) * 16;
            #pragma unroll
            for (int i = 0; i < 4; ++i) {
                const int r = wm * 64 + i * 16 + (l & 15);
                af[i] = *(const f16x8*)(ab + r * 128 + (kb ^ ((r & 7) << 4)));
            }
            #pragma unroll
            for (int i = 0; i < 4; ++i) {
                const int r = wn * 64 + i * 16 + (l & 15);
                bf[i] = *(const f16x8*)(bb + r * 128 + (kb ^ ((r & 7) << 4)));
            }
        }
        if (t + 2 < NT) STAGE_A(t + 2, (t + 2) % 3);
        __builtin_amdgcn_sched_barrier(0);
        __builtin_amdgcn_s_barrier();
        asm volatile("s_waitcnt lgkmcnt(0)" ::: "memory");
        __builtin_amdgcn_sched_barrier(0);
        __builtin_amdgcn_s_setprio(1);
        #pragma unroll
        for (int i = 0; i < 4; ++i)
            #pragma unroll
            for (int jj = 0; jj < 4; ++jj)
                acc[i][jj] = __builtin_amdgcn_mfma_f32_16x16x32_f16(af[i], bf[jj], acc[i][jj], 0, 0, 0);
        __builtin_amdgcn_s_setprio(0);
        __builtin_amdgcn_sched_barrier(0);

        // ===== phase 1: ks = 1 =====
        {
            const int kb = 64 + (l >> 4) * 16;
            #pragma unroll
            for (int i = 0; i < 4; ++i) {
                const int r = wm * 64 + i * 16 + (l & 15);
                af[i] = *(const f16x8*)(ab + r * 128 + (kb ^ ((r & 7) << 4)));
            }
            #pragma unroll
            for (int i = 0; i < 4; ++i) {
                const int r = wn * 64 + i * 16 + (l & 15);
                bf[i] = *(const f16x8*)(bb + r * 128 + (kb ^ ((r & 7) << 4)));
            }
        }
        if (t + 2 < NT) STAGE_B(t + 2, (t + 2) % 3);
        __builtin_amdgcn_sched_barrier(0);
        __builtin_amdgcn_s_barrier();
        asm volatile("s_waitcnt lgkmcnt(0)" ::: "memory");
        __builtin_amdgcn_sched_barrier(0);
        __builtin_amdgcn_s_setprio(1);
        #pragma unroll
        for (int i = 0; i < 4; ++i)
            #pragma unroll
            for (int jj = 0; jj < 4; ++jj)
                acc[i][jj] = __builtin_amdgcn_mfma_f32_16x16x32_f16(af[i], bf[jj], acc[i][jj], 0, 0, 0);
        __builtin_amdgcn_s_setprio(0);
        __builtin_amdgcn_sched_barrier(0);
    }
    #undef STAGE_A
    #undef STAGE_B
}

// Block -> tile map: 4 M-panels x 8 N-panels per XCD so A is fetched once
// chip-wide (L2-miss ~100 MB instead of ~400). bid&7 = XCD (round-robin).
__device__ __forceinline__ void tile_map(int bid, int& m0, int& n0) {
    const int xcd = bid & 7;
    const int idx = bid >> 3;            // 0..31
    m0 = (xcd * 4 + (idx >> 3)) * 256;   // 32 M-tiles
    n0 = (idx & 7) * 128;                // 8 N-tiles
}

// GEMM1: g_xs [8192][3072] x g_WpT[n][3072] -> pi*tanh(acc*2^-24 + bias) -> g_ph[b][n][s]
__global__ __launch_bounds__(512) void gemm1(const float* __restrict__ bias) {
    __shared__ ushort lds[3 * 24576];   // 144 KB
    const int tid = threadIdx.x;
    const int wid = tid >> 6, l = tid & 63;
    int m0, n0;
    tile_map(blockIdx.x, m0, n0);
    const int wm = wid >> 1, wn = wid & 1;

    f32x4 acc[4][4];
    #pragma unroll
    for (int i = 0; i < 4; ++i)
        #pragma unroll
        for (int j = 0; j < 4; ++j) acc[i][j] = (f32x4){0.f, 0.f, 0.f, 0.f};

    gemm_mainloop<K1_>(g_xs, g_WpT, lds, m0, n0, wid, l, wm, wn, acc);

    const int r4 = (l >> 4) * 4;
    const int cn = l & 15;
    #pragma unroll
    for (int i = 0; i < 4; ++i) {
        const int mg = m0 + wm * 64 + i * 16 + r4;
        const int bidx = mg >> 11;
        const int sg = mg & 2047;
        #pragma unroll
        for (int jj = 0; jj < 4; ++jj) {
            const int ng = n0 + wn * 64 + jj * 16 + cn;
            const float bb = bias[ng];
            float4 o;
            o.x = PI_ * tanhf(fmaf(acc[i][jj][0], INVSC2_, bb));
            o.y = PI_ * tanhf(fmaf(acc[i][jj][1], INVSC2_, bb));
            o.z = PI_ * tanhf(fmaf(acc[i][jj][2], INVSC2_, bb));
            o.w = PI_ * tanhf(fmaf(acc[i][jj][3], INVSC2_, bb));
            *(float4*)(g_ph + ((size_t)bidx * HN_ + ng) * S_ + sg) = o;
        }
    }
}

// GEMM3: g_phT [8192][1024] x g_WoT[d][1024] + bias -> Y [8192][1024] f32
__global__ __launch_bounds__(512) void gemm3(const float* __restrict__ bias,
                                             float* __restrict__ Y) {
    __shared__ ushort lds[3 * 24576];   // 144 KB
    const int tid = threadIdx.x;
    const int wid = tid >> 6, l = tid & 63;
    int m0, n0;
    tile_map(blockIdx.x, m0, n0);
    const int wm = wid >> 1, wn = wid & 1;

    f32x4 acc[4][4];
    #pragma unroll
    for (int i = 0; i < 4; ++i)
        #pragma unroll
        for (int j = 0; j < 4; ++j) acc[i][j] = (f32x4){0.f, 0.f, 0.f, 0.f};

    gemm_mainloop<K3_>(g_phT, g_WoT, lds, m0, n0, wid, l, wm, wn, acc);

    const int r4 = (l >> 4) * 4;
    const int cn = l & 15;
    #pragma unroll
    for (int i = 0; i < 4; ++i) {
        const int mg = m0 + wm * 64 + i * 16 + r4;
        #pragma unroll
        for (int jj = 0; jj < 4; ++jj) {
            const int ng = n0 + wn * 64 + jj * 16 + cn;
            const float bb = bias[ng];
            #pragma unroll
            for (int r = 0; r < 4; ++r)
                Y[(size_t)(mg + r) * D_ + ng] = acc[i][jj][r] + bb;
        }
    }
}

// ---------------------------------------------------------------------------
// Kuramoto (unchanged, verified): one wave per (b, hn), 10 iters in registers.
// ---------------------------------------------------------------------------
__global__ __launch_bounds__(256) void kuramoto(const int* __restrict__ mask,
                                                const float* __restrict__ natf,
                                                const float* __restrict__ coup) {
    const int wave = blockIdx.x * 4 + (threadIdx.x >> 6);
    const int lane = threadIdx.x & 63;
    const int b = wave >> 10;
    const int hn = wave & 1023;
    const int h = hn >> 7;

    const float wf = natf[hn];
    const float K = coup[h];

    const float* base = g_ph + ((size_t)b * HN_ + hn) * S_;

    float ph[32];
    #pragma unroll
    for (int i = 0; i < 8; ++i) {
        float4 v = *(const float4*)(base + i * 256 + lane * 4);
        ph[4 * i + 0] = v.x; ph[4 * i + 1] = v.y;
        ph[4 * i + 2] = v.z; ph[4 * i + 3] = v.w;
    }

    const int* mb = mask + b * S_;
    unsigned mbits = 0;
    #pragma unroll
    for (int i = 0; i < 8; ++i) {
        int4 mv = *(const int4*)(mb + i * 256 + lane * 4);
        mbits |= (mv.x != 0 ? 1u : 0u) << (4 * i + 0);
        mbits |= (mv.y != 0 ? 1u : 0u) << (4 * i + 1);
        mbits |= (mv.z != 0 ? 1u : 0u) << (4 * i + 2);
        mbits |= (mv.w != 0 ? 1u : 0u) << (4 * i + 3);
    }

    for (int it = 0; it < ITERS_; ++it) {
        float s[32], c[32];
        float ls = 0.f, lc = 0.f;
        #pragma unroll
        for (int i = 0; i < 32; ++i) {
            s[i] = __sinf(ph[i]);
            c[i] = __cosf(ph[i]);
            const float mf = (float)((mbits >> i) & 1u);
            ls = fmaf(mf, s[i], ls);
            lc = fmaf(mf, c[i], lc);
        }
        #pragma unroll
        for (int off = 32; off; off >>= 1) {
            ls += __shfl_xor(ls, off);
            lc += __shfl_xor(lc, off);
        }
        const float ms = ls * (1.f / 2048.f);
        const float mc = lc * (1.f / 2048.f);
        #pragma unroll
        for (int i = 0; i < 32; ++i) {
            const float dth = fmaf(K, fmaf(s[i], mc, -c[i] * ms), wf);
            float t = fmaf(DT_, dth, ph[i]) + PI_;
            t -= TWOPI_ * floorf(t * INV2PI_);
            ph[i] = t - PI_;
        }
    }

    ushort* ob = g_phh + ((size_t)b * HN_ + hn) * S_;
    #pragma unroll
    for (int i = 0; i < 8; ++i) {
        ushort4 o;
        o.x = f2h(ph[4 * i + 0]); o.y = f2h(ph[4 * i + 1]);
        o.z = f2h(ph[4 * i + 2]); o.w = f2h(ph[4 * i + 3]);
        *(ushort4*)(ob + i * 256 + lane * 4) = o;
    }
}

// ---------------------------------------------------------------------------
// g_phh [b][hn][s] fp16 -> g_phT [(b,s)][hn] fp16  (64x64 tiles, unchanged)
// ---------------------------------------------------------------------------
__global__ __launch_bounds__(256) void transpose_ph() {
    __shared__ ushort t[64][72];
    const int b = blockIdx.z;
    const int h0 = blockIdx.y * 64;
    const int s0 = blockIdx.x * 64;
    const int r = threadIdx.x >> 2;
    const int c = (threadIdx.x & 3) * 16;
    const ushort* src = g_phh + ((size_t)b * HN_ + h0 + r) * S_ + s0 + c;
    *(int4*)&t[r][c] = *(const int4*)src;
    *(int4*)&t[r][c + 8] = *(const int4*)(src + 8);
    __syncthreads();
    ushort o[16];
    #pragma unroll
    for (int j = 0; j < 16; ++j) o[j] = t[c + j][r];
    ushort* dst = g_phT + ((size_t)(b * S_ + s0 + r)) * HN_ + h0 + c;
    int4 o0, o1;
    o0.x = pack2(o[0], o[1]);   o0.y = pack2(o[2], o[3]);
    o0.z = pack2(o[4], o[5]);   o0.w = pack2(o[6], o[7]);
    o1.x = pack2(o[8], o[9]);   o1.y = pack2(o[10], o[11]);
    o1.z = pack2(o[12], o[13]); o1.w = pack2(o[14], o[15]);
    *(int4*)dst = o0;
    *(int4*)(dst + 8) = o1;
}

extern "C" void kernel_launch(void* const* d_in, const int* in_sizes, int n_in,
                              void* d_out, int out_size, void* d_ws, size_t ws_size,
                              hipStream_t stream) {
    const float* x    = (const float*)d_in[0];
    const int*   mask = (const int*)d_in[1];
    const float* Wp   = (const float*)d_in[2];
    const float* bp   = (const float*)d_in[3];
    const float* natf = (const float*)d_in[4];
    const float* coup = (const float*)d_in[5];
    const float* Wo   = (const float*)d_in[6];
    const float* bo   = (const float*)d_in[7];
    float* y = (float*)d_out;

    split_x  <<<dim3(8192),         256, 0, stream>>>(x);
    splitT_Wp<<<dim3(16, 16),       256, 0, stream>>>(Wp);
    castT_Wo <<<dim3(16, 16),       256, 0, stream>>>(Wo);
    gemm1    <<<dim3(256),          512, 0, stream>>>(bp);
    kuramoto <<<dim3(1024),         256, 0, stream>>>(mask, natf, coup);
    transpose_ph<<<dim3(32, 16, 4), 256, 0, stream>>>();
    gemm3    <<<dim3(256),          512, 0, stream>>>(bo, y);
}

// Round 6
// 158.558 us; speedup vs baseline: 3.0616x; 1.0011x over previous
//
#include <hip/hip_runtime.h>
#include <math.h>

#define S_ 2048
#define D_ 1024
#define HN_ 1024
#define B_ 4
#define M_ 8192
#define K1_ 3072
#define K3_ 1024
#define ITERS_ 10
#define DT_ 0.1f
#define PI_ 3.14159265358979323846f
#define TWOPI_ 6.28318530717958647692f
#define INV2PI_ 0.15915494309189533577f
#define SCALE_ 4096.0f
#define INVSC2_ (1.0f / 16777216.0f)   // 2^-24

typedef __attribute__((ext_vector_type(8))) _Float16 f16x8;
typedef __attribute__((ext_vector_type(4))) float f32x4;

// static scratch
__device__ ushort g_xs [(size_t)M_ * K1_];      // x split [a|a|b] fp16, scaled 4096
__device__ ushort g_WpT[(size_t)HN_ * K1_];     // Wp^T split [a|b|a] fp16, scaled 4096
__device__ float  g_ph [(size_t)B_ * HN_ * S_]; // phases f32 [b][hn][s]
__device__ ushort g_phh[(size_t)B_ * HN_ * S_]; // final phases fp16 [b][hn][s]
__device__ ushort g_phT[(size_t)M_ * HN_];      // phases fp16 [(b,s)][hn]
__device__ ushort g_WoT[(size_t)D_ * HN_];      // Wo^T fp16 [d][hn] (unscaled)

__device__ __forceinline__ ushort f2h(float f) {
    union { _Float16 h; ushort u; } v; v.h = (_Float16)f; return v.u;
}
__device__ __forceinline__ void split2s(float x, ushort& A, ushort& Bc) {
    const float xs = x * SCALE_;
    union { _Float16 h; ushort u; } va, vb;
    va.h = (_Float16)xs;
    const float r = xs - (float)va.h;   // exact
    vb.h = (_Float16)r;
    A = va.u; Bc = vb.u;
}
__device__ __forceinline__ void gload16(const void* g, void* l) {
    __builtin_amdgcn_global_load_lds(
        (const __attribute__((address_space(1))) void*)g,
        (__attribute__((address_space(3))) void*)l, 16, 0, 0);
}
__device__ __forceinline__ int pack2(ushort a, ushort b) {
    return (int)(unsigned)a | ((int)(unsigned)b << 16);
}

// ---------------------------------------------------------------------------
// prep kernels (unchanged, verified)
// ---------------------------------------------------------------------------
__global__ __launch_bounds__(256) void split_x(const float* __restrict__ X) {
    const int idx = blockIdx.x * 256 + threadIdx.x;
    const float4 v = ((const float4*)X)[idx];
    const int m  = idx >> 8;
    const int k4 = (idx & 255) * 4;
    ushort a[4], b[4];
    split2s(v.x, a[0], b[0]);
    split2s(v.y, a[1], b[1]);
    split2s(v.z, a[2], b[2]);
    split2s(v.w, a[3], b[3]);
    ushort* row = g_xs + (size_t)m * K1_ + k4;
    int2 oa; oa.x = pack2(a[0], a[1]); oa.y = pack2(a[2], a[3]);
    int2 ob; ob.x = pack2(b[0], b[1]); ob.y = pack2(b[2], b[3]);
    *(int2*)(row)        = oa;
    *(int2*)(row + 1024) = oa;
    *(int2*)(row + 2048) = ob;
}

__global__ __launch_bounds__(256) void splitT_Wp(const float* __restrict__ Wp) {
    __shared__ float t[64][68];
    const int k0 = blockIdx.x * 64;
    const int n0 = blockIdx.y * 64;
    const int r = threadIdx.x >> 2;
    const int c = (threadIdx.x & 3) * 16;
    const float* src = Wp + (size_t)(k0 + r) * HN_ + n0 + c;
    #pragma unroll
    for (int q = 0; q < 4; ++q)
        *(float4*)&t[r][c + 4 * q] = ((const float4*)src)[q];
    __syncthreads();
    ushort ha[16], hb[16];
    #pragma unroll
    for (int j = 0; j < 16; ++j)
        split2s(t[c + j][r], ha[j], hb[j]);
    int4 a0, a1, b0, b1;
    a0.x = pack2(ha[0], ha[1]);   a0.y = pack2(ha[2], ha[3]);
    a0.z = pack2(ha[4], ha[5]);   a0.w = pack2(ha[6], ha[7]);
    a1.x = pack2(ha[8], ha[9]);   a1.y = pack2(ha[10], ha[11]);
    a1.z = pack2(ha[12], ha[13]); a1.w = pack2(ha[14], ha[15]);
    b0.x = pack2(hb[0], hb[1]);   b0.y = pack2(hb[2], hb[3]);
    b0.z = pack2(hb[4], hb[5]);   b0.w = pack2(hb[6], hb[7]);
    b1.x = pack2(hb[8], hb[9]);   b1.y = pack2(hb[10], hb[11]);
    b1.z = pack2(hb[12], hb[13]); b1.w = pack2(hb[14], hb[15]);
    ushort* dst = g_WpT + (size_t)(n0 + r) * K1_ + k0 + c;
    *(int4*)(dst)            = a0; *(int4*)(dst + 8)        = a1;
    *(int4*)(dst + 1024)     = b0; *(int4*)(dst + 1032)     = b1;
    *(int4*)(dst + 2048)     = a0; *(int4*)(dst + 2056)     = a1;
}

__global__ __launch_bounds__(256) void castT_Wo(const float* __restrict__ Wo) {
    __shared__ float t[64][68];
    const int k0 = blockIdx.x * 64;   // hn
    const int n0 = blockIdx.y * 64;   // d
    const int r = threadIdx.x >> 2;
    const int c = (threadIdx.x & 3) * 16;
    const float* src = Wo + (size_t)(k0 + r) * D_ + n0 + c;
    #pragma unroll
    for (int q = 0; q < 4; ++q)
        *(float4*)&t[r][c + 4 * q] = ((const float4*)src)[q];
    __syncthreads();
    ushort h[16];
    #pragma unroll
    for (int j = 0; j < 16; ++j) h[j] = f2h(t[c + j][r]);
    ushort* dst = g_WoT + (size_t)(n0 + r) * HN_ + k0 + c;
    int4 o0, o1;
    o0.x = pack2(h[0], h[1]);   o0.y = pack2(h[2], h[3]);
    o0.z = pack2(h[4], h[5]);   o0.w = pack2(h[6], h[7]);
    o1.x = pack2(h[8], h[9]);   o1.y = pack2(h[10], h[11]);
    o1.z = pack2(h[12], h[13]); o1.w = pack2(h[14], h[15]);
    *(int4*)dst = o0;
    *(int4*)(dst + 8) = o1;
}

// ---------------------------------------------------------------------------
// MFMA main loop, BM=128 x BN=256, BK=64, 8 waves (2M x 4N), 512 threads.
// m201-style 4-phase schedule per K-tile:
//   top: vmcnt(6) -> s_barrier      (3-buffer rotation, loads span 2 K-tiles)
//   p0: ds_read A{0,1}+B{0,1} | stage A-half0(kt+2) | bar,lgkm0 | 8 MFMA q(0,0)
//   p1: ds_read B{2,3}        | stage A-half1       | bar,lgkm0 | 8 MFMA q(0,1)
//   p2: ds_read A{2,3}        | stage B-half0       | bar,lgkm0 | 8 MFMA q(1,1)
//   p3: (regs reused)         | stage B-half1       | bar       | 8 MFMA q(1,0)
// Buffer layout per 48KB buf: A 128x128B at 0, B 256x128B at +16KB.
// T2 swizzle: LDS dest linear; global source pre-inverse-swizzled (swzo);
// ds_read addr kb ^ ((row&7)<<4). Race audit: stage(kt+2) writes buf consumed
// at kt-1; readers' last ds_reads (p2) complete before their own lgkm0+MFMA,
// which precede kt's top barrier, which precedes any stage(kt+2) issue.
// ---------------------------------------------------------------------------
template<int KDIM>
__device__ __forceinline__ void gemm_mainloop(const ushort* __restrict__ A,
                                              const ushort* __restrict__ Bm,
                                              ushort* lds,
                                              int m0, int n0, int wid, int l,
                                              int wm, int wn,
                                              f32x4 (&acc)[4][4]) {
    constexpr int NT = KDIM / 64;
    const int r8   = l >> 3;                       // 0..7
    const int swzo = ((l & 7) * 16) ^ (r8 << 4);   // inverse-swizzled source byte
    const int l15  = l & 15;
    const int kq16 = (l >> 4) * 16;

    #define STG_A(GB, BUF, H)                                                     \
        gload16((const char*)(A + (size_t)(m0 + (H)*64 + wid*8 + r8) * KDIM) + (GB), \
                (char*)lds + (BUF)*49152 + ((H)*64 + wid*8)*128)
    #define STG_B(GB, BUF, H) do {                                                \
        _Pragma("unroll")                                                         \
        for (int j_ = 0; j_ < 2; ++j_)                                            \
            gload16((const char*)(Bm + (size_t)(n0 + (H)*128 + (wid*2+j_)*8 + r8) * KDIM) + (GB), \
                    (char*)lds + (BUF)*49152 + 16384 + ((H)*128 + (wid*2+j_)*8)*128); \
    } while (0)
    #define STG_KT(T, BUF) do {                                                   \
        const size_t gb_ = (size_t)(T) * 128 + swzo;                              \
        STG_A(gb_, BUF, 0); STG_A(gb_, BUF, 1);                                   \
        STG_B(gb_, BUF, 0); STG_B(gb_, BUF, 1);                                   \
    } while (0)

    #define LD_A(MIB) do {                                                        \
        _Pragma("unroll")                                                         \
        for (int mi_ = 0; mi_ < 2; ++mi_)                                         \
            _Pragma("unroll")                                                     \
            for (int ks_ = 0; ks_ < 2; ++ks_) {                                   \
                const int r_ = wm*64 + ((MIB)+mi_)*16 + l15;                      \
                Aa[mi_][ks_] = *(const f16x8*)(ab + r_*128 +                      \
                    ((ks_*64 + kq16) ^ ((r_ & 7) << 4)));                         \
            }                                                                     \
    } while (0)
    #define LD_B(NIB) do {                                                        \
        _Pragma("unroll")                                                         \
        for (int ni_ = 0; ni_ < 2; ++ni_)                                         \
            _Pragma("unroll")                                                     \
            for (int ks_ = 0; ks_ < 2; ++ks_) {                                   \
                const int r_ = wn*64 + ((NIB)+ni_)*16 + l15;                      \
                Bb[(NIB)+ni_][ks_] = *(const f16x8*)(bb + r_*128 +                \
                    ((ks_*64 + kq16) ^ ((r_ & 7) << 4)));                         \
            }                                                                     \
    } while (0)

    #define PH_BAR_LGKM do {                                                      \
        __builtin_amdgcn_sched_barrier(0);                                        \
        __builtin_amdgcn_s_barrier();                                             \
        asm volatile("s_waitcnt lgkmcnt(0)" ::: "memory");                        \
        __builtin_amdgcn_sched_barrier(0);                                        \
    } while (0)
    #define PH_BAR do {                                                           \
        __builtin_amdgcn_sched_barrier(0);                                        \
        __builtin_amdgcn_s_barrier();                                             \
        __builtin_amdgcn_sched_barrier(0);                                        \
    } while (0)

    #define PH_MFMA(MIB, NIB) do {                                                \
        __builtin_amdgcn_s_setprio(1);                                            \
        _Pragma("unroll")                                                         \
        for (int mi_ = 0; mi_ < 2; ++mi_)                                         \
            _Pragma("unroll")                                                     \
            for (int ni_ = 0; ni_ < 2; ++ni_)                                     \
                _Pragma("unroll")                                                 \
                for (int ks_ = 0; ks_ < 2; ++ks_)                                 \
                    acc[(MIB)+mi_][(NIB)+ni_] =                                   \
                        __builtin_amdgcn_mfma_f32_16x16x32_f16(                   \
                            Aa[mi_][ks_], Bb[(NIB)+ni_][ks_],                     \
                            acc[(MIB)+mi_][(NIB)+ni_], 0, 0, 0);                  \
        __builtin_amdgcn_s_setprio(0);                                            \
        __builtin_amdgcn_sched_barrier(0);                                        \
    } while (0)

    STG_KT(0, 0);
    STG_KT(1, 1);

    int bc = 0;  // buffer of current K-tile
    for (int kt = 0; kt < NT; ++kt) {
        if (kt < NT - 1) asm volatile("s_waitcnt vmcnt(6)" ::: "memory");
        else             asm volatile("s_waitcnt vmcnt(0)" ::: "memory");
        PH_BAR;

        const char* ab = (const char*)lds + bc * 49152;
        const char* bb = ab + 16384;
        int bn = bc + 2; if (bn >= 3) bn -= 3;
        const bool st = (kt + 2 < NT);
        const size_t gb = (size_t)(kt + 2) * 128 + swzo;

        f16x8 Aa[2][2], Bb[4][2];

        // ---- phase 0: quadrant (m 0-1, n 0-1) ----
        LD_A(0); LD_B(0);
        if (st) STG_A(gb, bn, 0);
        PH_BAR_LGKM;
        PH_MFMA(0, 0);

        // ---- phase 1: quadrant (m 0-1, n 2-3) ----
        LD_B(2);
        if (st) STG_A(gb, bn, 1);
        PH_BAR_LGKM;
        PH_MFMA(0, 2);

        // ---- phase 2: quadrant (m 2-3, n 2-3) ----
        LD_A(2);
        if (st) STG_B(gb, bn, 0);
        PH_BAR_LGKM;
        PH_MFMA(2, 2);

        // ---- phase 3: quadrant (m 2-3, n 0-1), all regs already live ----
        if (st) STG_B(gb, bn, 1);
        PH_BAR;
        PH_MFMA(2, 0);

        bc = bc + 1; if (bc >= 3) bc -= 3;
    }
    #undef STG_A
    #undef STG_B
    #undef STG_KT
    #undef LD_A
    #undef LD_B
    #undef PH_BAR_LGKM
    #undef PH_BAR
    #undef PH_MFMA
}

// Block -> tile map: per XCD 8 M-panels x 4 N-panels (A fetched once chip-wide)
__device__ __forceinline__ void tile_map(int bid, int& m0, int& n0) {
    const int xcd = bid & 7;
    const int idx = bid >> 3;              // 0..31
    m0 = (xcd * 8 + (idx >> 2)) * 128;     // 64 M-tiles
    n0 = (idx & 3) * 256;                  // 4 N-tiles
}

// GEMM1: g_xs [8192][3072] x g_WpT[n][3072] -> pi*tanh(acc*2^-24 + bias) -> g_ph[b][n][s]
__global__ __launch_bounds__(512, 2) void gemm1(const float* __restrict__ bias) {
    __shared__ ushort lds[3 * 24576];   // 144 KB
    const int tid = threadIdx.x;
    const int wid = tid >> 6, l = tid & 63;
    int m0, n0;
    tile_map(blockIdx.x, m0, n0);
    const int wm = wid >> 2, wn = wid & 3;

    f32x4 acc[4][4];
    #pragma unroll
    for (int i = 0; i < 4; ++i)
        #pragma unroll
        for (int j = 0; j < 4; ++j) acc[i][j] = (f32x4){0.f, 0.f, 0.f, 0.f};

    gemm_mainloop<K1_>(g_xs, g_WpT, lds, m0, n0, wid, l, wm, wn, acc);

    const int r4 = (l >> 4) * 4;
    const int cn = l & 15;
    #pragma unroll
    for (int i = 0; i < 4; ++i) {
        const int mg = m0 + wm * 64 + i * 16 + r4;
        const int bidx = mg >> 11;
        const int sg = mg & 2047;
        #pragma unroll
        for (int jj = 0; jj < 4; ++jj) {
            const int ng = n0 + wn * 64 + jj * 16 + cn;
            const float bb = bias[ng];
            float4 o;
            o.x = PI_ * tanhf(fmaf(acc[i][jj][0], INVSC2_, bb));
            o.y = PI_ * tanhf(fmaf(acc[i][jj][1], INVSC2_, bb));
            o.z = PI_ * tanhf(fmaf(acc[i][jj][2], INVSC2_, bb));
            o.w = PI_ * tanhf(fmaf(acc[i][jj][3], INVSC2_, bb));
            *(float4*)(g_ph + ((size_t)bidx * HN_ + ng) * S_ + sg) = o;
        }
    }
}

// GEMM3: g_phT [8192][1024] x g_WoT[d][1024] + bias -> Y [8192][1024] f32
__global__ __launch_bounds__(512, 2) void gemm3(const float* __restrict__ bias,
                                                float* __restrict__ Y) {
    __shared__ ushort lds[3 * 24576];   // 144 KB
    const int tid = threadIdx.x;
    const int wid = tid >> 6, l = tid & 63;
    int m0, n0;
    tile_map(blockIdx.x, m0, n0);
    const int wm = wid >> 2, wn = wid & 3;

    f32x4 acc[4][4];
    #pragma unroll
    for (int i = 0; i < 4; ++i)
        #pragma unroll
        for (int j = 0; j < 4; ++j) acc[i][j] = (f32x4){0.f, 0.f, 0.f, 0.f};

    gemm_mainloop<K3_>(g_phT, g_WoT, lds, m0, n0, wid, l, wm, wn, acc);

    const int r4 = (l >> 4) * 4;
    const int cn = l & 15;
    #pragma unroll
    for (int i = 0; i < 4; ++i) {
        const int mg = m0 + wm * 64 + i * 16 + r4;
        #pragma unroll
        for (int jj = 0; jj < 4; ++jj) {
            const int ng = n0 + wn * 64 + jj * 16 + cn;
            const float bb = bias[ng];
            #pragma unroll
            for (int r = 0; r < 4; ++r)
                Y[(size_t)(mg + r) * D_ + ng] = acc[i][jj][r] + bb;
        }
    }
}

// ---------------------------------------------------------------------------
// Kuramoto (unchanged, verified): one wave per (b, hn), 10 iters in registers.
// ---------------------------------------------------------------------------
__global__ __launch_bounds__(256) void kuramoto(const int* __restrict__ mask,
                                                const float* __restrict__ natf,
                                                const float* __restrict__ coup) {
    const int wave = blockIdx.x * 4 + (threadIdx.x >> 6);
    const int lane = threadIdx.x & 63;
    const int b = wave >> 10;
    const int hn = wave & 1023;
    const int h = hn >> 7;

    const float wf = natf[hn];
    const float K = coup[h];

    const float* base = g_ph + ((size_t)b * HN_ + hn) * S_;

    float ph[32];
    #pragma unroll
    for (int i = 0; i < 8; ++i) {
        float4 v = *(const float4*)(base + i * 256 + lane * 4);
        ph[4 * i + 0] = v.x; ph[4 * i + 1] = v.y;
        ph[4 * i + 2] = v.z; ph[4 * i + 3] = v.w;
    }

    const int* mb = mask + b * S_;
    unsigned mbits = 0;
    #pragma unroll
    for (int i = 0; i < 8; ++i) {
        int4 mv = *(const int4*)(mb + i * 256 + lane * 4);
        mbits |= (mv.x != 0 ? 1u : 0u) << (4 * i + 0);
        mbits |= (mv.y != 0 ? 1u : 0u) << (4 * i + 1);
        mbits |= (mv.z != 0 ? 1u : 0u) << (4 * i + 2);
        mbits |= (mv.w != 0 ? 1u : 0u) << (4 * i + 3);
    }

    for (int it = 0; it < ITERS_; ++it) {
        float s[32], c[32];
        float ls = 0.f, lc = 0.f;
        #pragma unroll
        for (int i = 0; i < 32; ++i) {
            s[i] = __sinf(ph[i]);
            c[i] = __cosf(ph[i]);
            const float mf = (float)((mbits >> i) & 1u);
            ls = fmaf(mf, s[i], ls);
            lc = fmaf(mf, c[i], lc);
        }
        #pragma unroll
        for (int off = 32; off; off >>= 1) {
            ls += __shfl_xor(ls, off);
            lc += __shfl_xor(lc, off);
        }
        const float ms = ls * (1.f / 2048.f);
        const float mc = lc * (1.f / 2048.f);
        #pragma unroll
        for (int i = 0; i < 32; ++i) {
            const float dth = fmaf(K, fmaf(s[i], mc, -c[i] * ms), wf);
            float t = fmaf(DT_, dth, ph[i]) + PI_;
            t -= TWOPI_ * floorf(t * INV2PI_);
            ph[i] = t - PI_;
        }
    }

    ushort* ob = g_phh + ((size_t)b * HN_ + hn) * S_;
    #pragma unroll
    for (int i = 0; i < 8; ++i) {
        ushort4 o;
        o.x = f2h(ph[4 * i + 0]); o.y = f2h(ph[4 * i + 1]);
        o.z = f2h(ph[4 * i + 2]); o.w = f2h(ph[4 * i + 3]);
        *(ushort4*)(ob + i * 256 + lane * 4) = o;
    }
}

// ---------------------------------------------------------------------------
// g_phh [b][hn][s] fp16 -> g_phT [(b,s)][hn] fp16  (64x64 tiles, unchanged)
// ---------------------------------------------------------------------------
__global__ __launch_bounds__(256) void transpose_ph() {
    __shared__ ushort t[64][72];
    const int b = blockIdx.z;
    const int h0 = blockIdx.y * 64;
    const int s0 = blockIdx.x * 64;
    const int r = threadIdx.x >> 2;
    const int c = (threadIdx.x & 3) * 16;
    const ushort* src = g_phh + ((size_t)b * HN_ + h0 + r) * S_ + s0 + c;
    *(int4*)&t[r][c] = *(const int4*)src;
    *(int4*)&t[r][c + 8] = *(const int4*)(src + 8);
    __syncthreads();
    ushort o[16];
    #pragma unroll
    for (int j = 0; j < 16; ++j) o[j] = t[c + j][r];
    ushort* dst = g_phT + ((size_t)(b * S_ + s0 + r)) * HN_ + h0 + c;
    int4 o0, o1;
    o0.x = pack2(o[0], o[1]);   o0.y = pack2(o[2], o[3]);
    o0.z = pack2(o[4], o[5]);   o0.w = pack2(o[6], o[7]);
    o1.x = pack2(o[8], o[9]);   o1.y = pack2(o[10], o[11]);
    o1.z = pack2(o[12], o[13]); o1.w = pack2(o[14], o[15]);
    *(int4*)dst = o0;
    *(int4*)(dst + 8) = o1;
}

extern "C" void kernel_launch(void* const* d_in, const int* in_sizes, int n_in,
                              void* d_out, int out_size, void* d_ws, size_t ws_size,
                              hipStream_t stream) {
    const float* x    = (const float*)d_in[0];
    const int*   mask = (const int*)d_in[1];
    const float* Wp   = (const float*)d_in[2];
    const float* bp   = (const float*)d_in[3];
    const float* natf = (const float*)d_in[4];
    const float* coup = (const float*)d_in[5];
    const float* Wo   = (const float*)d_in[6];
    const float* bo   = (const float*)d_in[7];
    float* y = (float*)d_out;

    split_x  <<<dim3(8192),         256, 0, stream>>>(x);
    splitT_Wp<<<dim3(16, 16),       256, 0, stream>>>(Wp);
    castT_Wo <<<dim3(16, 16),       256, 0, stream>>>(Wo);
    gemm1    <<<dim3(256),          512, 0, stream>>>(bp);
    kuramoto <<<dim3(1024),         256, 0, stream>>>(mask, natf, coup);
    transpose_ph<<<dim3(32, 16, 4), 256, 0, stream>>>();
    gemm3    <<<dim3(256),          512, 0, stream>>>(bo, y);
}